// Round 7
// baseline (453.453 us; speedup 1.0000x reference)
//
#include <hip/hip_runtime.h>
#include <hip/hip_fp16.h>

// MoleculeGCN: 2-layer GCN, N=100000, 128->64->64, E=1600000 + self-loops.
// CSR-by-dst with interleaved {src,norm} 8B records. Intermediate features h1/h2
// stored FP16 (halves the gather traffic; fp32 math throughout). GEMM2 fused
// into aggregate-1's epilogue (readlane-broadcast row x W2-in-LDS), eliminating
// the a1 round-trip and a kernel. Round-5 lesson checked: 16KB LDS caps at 10
// blocks/CU > wave cap (8) -> no occupancy loss from the fusion this time.

#define GSB 2048  // grid-stride blocks for edge-parallel work
#define SCAN_BS 256

__device__ __forceinline__ float h2f(unsigned short u) {
  __half_raw r; r.x = u;
  return __half2float((__half)r);
}

// ---------- edge dtype detect (int64 vs int32), SAMPLED ----------
// int64: odd 32-bit words are high halves of node ids (< 2^17) -> all zero.
// int32: odd words are random node ids -> 16384 all-zero samples impossible.
__global__ __launch_bounds__(256) void detect_dtype_kernel(const unsigned* __restrict__ w,
                                                           int E, unsigned* __restrict__ flag) {
  __shared__ unsigned sacc;
  if (threadIdx.x == 0) sacc = 0u;
  __syncthreads();
  int ns = min(16384, E);
  unsigned acc = 0;
  for (int i = threadIdx.x; i < ns; i += 256) acc |= w[2 * i + 1];
  if (__any(acc != 0) && (threadIdx.x & 63) == 0) sacc = 1u;  // LDS, not global atomic
  __syncthreads();
  if (threadIdx.x == 0) *flag = sacc;
}

__device__ __forceinline__ int edge_src(const int* w, long e, long E, bool is64) {
  return is64 ? w[2 * e] : w[e];
}
__device__ __forceinline__ int edge_dst(const int* w, long e, long E, bool is64) {
  return is64 ? w[2 * (E + e)] : w[E + e];
}

// ---------- in-degree count (no LDS, full occupancy) ----------
__global__ __launch_bounds__(256) void count_deg_kernel(const int* __restrict__ w, int E,
                                                        const unsigned* __restrict__ flag,
                                                        int* __restrict__ cnt) {
  bool is64 = (*flag == 0u);
  int stride = gridDim.x * blockDim.x;
  for (int e = blockIdx.x * blockDim.x + threadIdx.x; e < E; e += stride)
    atomicAdd(&cnt[edge_dst(w, e, E, is64)], 1);
}

// ---------- exclusive scan over cnt[N] -> offs[N+1] ----------
__global__ void scan_block_kernel(const int* __restrict__ cnt, int n, int* __restrict__ bsums) {
  __shared__ int s[SCAN_BS];
  int gid = blockIdx.x * SCAN_BS + threadIdx.x;
  s[threadIdx.x] = (gid < n) ? cnt[gid] : 0;
  __syncthreads();
  for (int st = SCAN_BS / 2; st > 0; st >>= 1) {
    if (threadIdx.x < st) s[threadIdx.x] += s[threadIdx.x + st];
    __syncthreads();
  }
  if (threadIdx.x == 0) bsums[blockIdx.x] = s[0];
}

// parallel single-block exclusive scan of bsums (chunked Hillis-Steele)
__global__ __launch_bounds__(512) void scan_bsums_kernel(int* __restrict__ bsums, int nb) {
  __shared__ int s[512];
  int carry = 0;
  for (int base = 0; base < nb; base += 512) {
    int g = base + threadIdx.x;
    int v = (g < nb) ? bsums[g] : 0;
    s[threadIdx.x] = v;
    __syncthreads();
    for (int st = 1; st < 512; st <<= 1) {
      int t = (threadIdx.x >= st) ? s[threadIdx.x - st] : 0;
      __syncthreads();
      s[threadIdx.x] += t;
      __syncthreads();
    }
    if (g < nb) bsums[g] = carry + s[threadIdx.x] - v;  // exclusive
    carry += s[511];
    __syncthreads();
  }
}

// offs (exclusive scan of cnt, + sentinel offs[n]=E) + dinv (fused)
__global__ void scan_apply_kernel(const int* __restrict__ cnt, int n,
                                  const int* __restrict__ bsums, int* __restrict__ offs,
                                  float* __restrict__ dinv, int E) {
  __shared__ int s[SCAN_BS];
  int gid = blockIdx.x * SCAN_BS + threadIdx.x;
  int v = (gid < n) ? cnt[gid] : 0;
  s[threadIdx.x] = v;
  __syncthreads();
  for (int st = 1; st < SCAN_BS; st <<= 1) {
    int t = (threadIdx.x >= st) ? s[threadIdx.x - st] : 0;
    __syncthreads();
    s[threadIdx.x] += t;
    __syncthreads();
  }
  if (gid < n) {
    offs[gid] = bsums[blockIdx.x] + s[threadIdx.x] - v;  // exclusive
    dinv[gid] = rsqrtf((float)v + 1.0f);                 // +1 = self loop
    if (gid == n - 1) offs[n] = E;                       // sentinel
  }
}

// ---------- counting-sort scatter: CSR by dst, 8B interleaved records ----------
__global__ void build_csr_kernel(const int* __restrict__ w, int E,
                                 const unsigned* __restrict__ flag,
                                 const int* __restrict__ offs, int* __restrict__ fill,
                                 const float* __restrict__ dinv,
                                 int2* __restrict__ csr) {
  bool is64 = (*flag == 0u);
  int stride = gridDim.x * blockDim.x;
  for (int e = blockIdx.x * blockDim.x + threadIdx.x; e < E; e += stride) {
    int s = edge_src(w, e, E, is64);
    int d = edge_dst(w, e, E, is64);
    int pos = offs[d] + atomicAdd(&fill[d], 1);
    int2 rec;
    rec.x = s;
    rec.y = __float_as_int(dinv[s] * dinv[d]);
    csr[pos] = rec;
  }
}

// ---------- GEMM1: H[n][64] = X[n][128] @ W[128][64], fp16 output ----------
__global__ __launch_bounds__(256) void gemm1_kernel(const float* __restrict__ X,
                                                    const float* __restrict__ W,
                                                    __half* __restrict__ H, int n) {
  __shared__ float Ws[128 * 64];
  for (int i = threadIdx.x; i < 128 * 64; i += 256) Ws[i] = W[i];
  __syncthreads();
  int row = blockIdx.x * 256 + threadIdx.x;
  if (row >= n) return;
  const float4* xr = (const float4*)(X + (size_t)row * 128);
  float acc[64];
#pragma unroll
  for (int c = 0; c < 64; c++) acc[c] = 0.f;
#pragma unroll 4
  for (int k4 = 0; k4 < 32; k4++) {
    float4 xv = xr[k4];
#pragma unroll
    for (int kk = 0; kk < 4; kk++) {
      float xs = (kk == 0) ? xv.x : (kk == 1) ? xv.y : (kk == 2) ? xv.z : xv.w;
      const float4* wr = (const float4*)&Ws[(k4 * 4 + kk) * 64];
#pragma unroll
      for (int c4 = 0; c4 < 16; c4++) {
        float4 wv = wr[c4];  // same address across lanes -> LDS broadcast
        acc[c4 * 4 + 0] += xs * wv.x;
        acc[c4 * 4 + 1] += xs * wv.y;
        acc[c4 * 4 + 2] += xs * wv.z;
        acc[c4 * 4 + 3] += xs * wv.w;
      }
    }
  }
  float4* ho = (float4*)(H + (size_t)row * 64);  // 64 halves = 8 x float4
#pragma unroll
  for (int g = 0; g < 8; g++) {
    union { __half2 h[4]; float4 f; } u;
    u.h[0] = __floats2half2_rn(acc[8 * g + 0], acc[8 * g + 1]);
    u.h[1] = __floats2half2_rn(acc[8 * g + 2], acc[8 * g + 3]);
    u.h[2] = __floats2half2_rn(acc[8 * g + 4], acc[8 * g + 5]);
    u.h[3] = __floats2half2_rn(acc[8 * g + 6], acc[8 * g + 7]);
    ho[g] = u.f;
  }
}

// ---------- shared gather core: one wave per node, 4 groups x 16 lanes ----------
// grp = lane>>4 (edge subset), fl = lane&15 (ushort4 = 4 halves of the row).
// Each 16-lane group reads one 128B fp16 row per iteration; 8-deep unroll x 4
// groups = 32 edges in flight. Butterfly reduce leaves the TOTAL in all lanes.
__device__ __forceinline__ float4 gather_row(
    const ushort4* __restrict__ H16, const int2* __restrict__ csr,
    int beg, int end, int lane, int grp, int fl) {
  float4 acc = {0.f, 0.f, 0.f, 0.f};
  for (int base = beg; base < end; base += 64) {
    int m = min(64, end - base);
    int sl = 0; float nl = 0.f;
    if (lane < m) {
      int2 rec = csr[base + lane];  // coalesced 8B
      sl = rec.x;
      nl = __int_as_float(rec.y);
    }
    int iters = ((m + 31) >> 5) << 3;  // 8 or 16; each iter covers 4 edges
    for (int j0 = 0; j0 < iters; j0 += 8) {
      int s[8]; float w[8]; ushort4 h[8];
#pragma unroll
      for (int t = 0; t < 8; t++) {
        int idx = (j0 + t) * 4 + grp;  // uniform within each 16-lane group
        s[t] = __shfl(sl, idx);
        w[t] = __shfl(nl, idx);
      }
#pragma unroll
      for (int t = 0; t < 8; t++) h[t] = H16[(size_t)s[t] * 16 + fl];  // 8 in flight
#pragma unroll
      for (int t = 0; t < 8; t++) {
        acc.x += h2f(h[t].x) * w[t];
        acc.y += h2f(h[t].y) * w[t];
        acc.z += h2f(h[t].z) * w[t];
        acc.w += h2f(h[t].w) * w[t];
      }
    }
  }
#pragma unroll
  for (int off2 = 32; off2 >= 16; off2 >>= 1) {  // butterfly: total lands in ALL lanes
    acc.x += __shfl_xor(acc.x, off2);
    acc.y += __shfl_xor(acc.y, off2);
    acc.z += __shfl_xor(acc.z, off2);
    acc.w += __shfl_xor(acc.w, off2);
  }
  return acc;
}

// ---------- layer 1 aggregate + fused GEMM2: h2 = relu(A@h1 + b1) @ W2 ----------
__global__ __launch_bounds__(256) void agg1_gemm2_kernel(
    const ushort4* __restrict__ H16, const int* __restrict__ offs,
    const int2* __restrict__ csr, const float* __restrict__ dinv,
    const float4* __restrict__ b1_4, const float* __restrict__ W2,
    __half* __restrict__ H2, int n) {
  __shared__ float W2s[64 * 64];  // 16KB: caps 10 blocks/CU > wave cap (8) -> free
  for (int i = threadIdx.x; i < 64 * 64; i += 256) W2s[i] = W2[i];
  __syncthreads();
  int wid = (blockIdx.x * 256 + threadIdx.x) >> 6;
  int lane = threadIdx.x & 63;
  if (wid >= n) return;
  int grp = lane >> 4, fl = lane & 15;
  float4 acc = gather_row(H16, csr, offs[wid], offs[wid + 1], lane, grp, fl);
  // self loop + bias + relu (all lanes hold the group-total; stays uniform)
  float di = dinv[wid];
  float d2 = di * di;
  ushort4 hv = H16[(size_t)wid * 16 + fl];
  float4 bv = b1_4[fl];
  float4 av;
  av.x = fmaxf(acc.x + h2f(hv.x) * d2 + bv.x, 0.f);
  av.y = fmaxf(acc.y + h2f(hv.y) * d2 + bv.y, 0.f);
  av.z = fmaxf(acc.z + h2f(hv.z) * d2 + bv.z, 0.f);
  av.w = fmaxf(acc.w + h2f(hv.w) * d2 + bv.w, 0.f);
  // fused row x W2: lane c owns output feature c. a1[k]=comp(k&3) of lane k>>2;
  // readlane broadcast + LDS read W2s[k*64+lane] (2 lanes/bank -> conflict-free).
  float o = 0.f;
#pragma unroll
  for (int k16 = 0; k16 < 16; k16++) {
    float a0 = __shfl(av.x, k16);
    float a1 = __shfl(av.y, k16);
    float a2 = __shfl(av.z, k16);
    float a3 = __shfl(av.w, k16);
    o += a0 * W2s[(k16 * 4 + 0) * 64 + lane];
    o += a1 * W2s[(k16 * 4 + 1) * 64 + lane];
    o += a2 * W2s[(k16 * 4 + 2) * 64 + lane];
    o += a3 * W2s[(k16 * 4 + 3) * 64 + lane];
  }
  H2[(size_t)wid * 64 + lane] = __float2half(o);  // 64 lanes x 2B = 128B contiguous
}

// ---------- layer 2 aggregate: out = A@h2 + b2 (fp32 out) ----------
__global__ __launch_bounds__(256) void agg2_kernel(
    const ushort4* __restrict__ H16, const int* __restrict__ offs,
    const int2* __restrict__ csr, const float* __restrict__ dinv,
    const float4* __restrict__ b2_4, float4* __restrict__ OUT4, int n) {
  int wid = (blockIdx.x * 256 + threadIdx.x) >> 6;
  int lane = threadIdx.x & 63;
  if (wid >= n) return;
  int grp = lane >> 4, fl = lane & 15;
  float4 acc = gather_row(H16, csr, offs[wid], offs[wid + 1], lane, grp, fl);
  if (lane < 16) {
    float di = dinv[wid];
    float d2 = di * di;
    ushort4 hv = H16[(size_t)wid * 16 + fl];
    float4 bv = b2_4[fl];
    acc.x += h2f(hv.x) * d2 + bv.x;
    acc.y += h2f(hv.y) * d2 + bv.y;
    acc.z += h2f(hv.z) * d2 + bv.z;
    acc.w += h2f(hv.w) * d2 + bv.w;
    OUT4[(size_t)wid * 16 + fl] = acc;  // 16 lanes x 16B = coalesced 256B row
  }
}

extern "C" void kernel_launch(void* const* d_in, const int* in_sizes, int n_in,
                              void* d_out, int out_size, void* d_ws, size_t ws_size,
                              hipStream_t stream) {
  const float* x  = (const float*)d_in[0];
  const int*   ei = (const int*)d_in[1];
  const float* W1 = (const float*)d_in[2];
  const float* b1 = (const float*)d_in[3];
  const float* W2 = (const float*)d_in[4];
  const float* b2 = (const float*)d_in[5];
  float* out = (float*)d_out;

  const int N = in_sizes[0] / 128;
  const int E = in_sizes[1] / 2;

  // ---- workspace carve-up (256B aligned) ----
  size_t off = 0;
  char* base = (char*)d_ws;
  auto alloc = [&](size_t bytes) -> void* {
    void* p = base + off;
    off += (bytes + 255) & ~(size_t)255;
    return p;
  };
  int*      cnt  = (int*)alloc((size_t)N * 4);      // } zeroed as one region
  int*      fill = (int*)alloc((size_t)N * 4);      // }
  unsigned* flag = (unsigned*)alloc(256);           // }
  size_t zero_bytes = off;
  int*   offs  = (int*)alloc((size_t)(N + 1) * 4);
  float* dinv  = (float*)alloc((size_t)N * 4);
  int nb = (N + SCAN_BS - 1) / SCAN_BS;
  int*   bsums = (int*)alloc((size_t)nb * 4);
  int2*  csr   = (int2*)alloc((size_t)E * 8);
  __half* h1   = (__half*)alloc((size_t)N * 64 * 2);
  __half* h2   = (__half*)alloc((size_t)N * 64 * 2);

  hipMemsetAsync(d_ws, 0, zero_bytes, stream);

  int gemm_blocks = (N + 255) / 256;
  int agg_blocks = (N + 3) / 4;

  // ---- graph prep (shared by both layers) ----
  detect_dtype_kernel<<<1, 256, 0, stream>>>((const unsigned*)ei, E, flag);
  count_deg_kernel<<<GSB, 256, 0, stream>>>(ei, E, flag, cnt);
  scan_block_kernel<<<nb, SCAN_BS, 0, stream>>>(cnt, N, bsums);
  scan_bsums_kernel<<<1, 512, 0, stream>>>(bsums, nb);
  scan_apply_kernel<<<nb, SCAN_BS, 0, stream>>>(cnt, N, bsums, offs, dinv, E);
  build_csr_kernel<<<GSB, 256, 0, stream>>>(ei, E, flag, offs, fill, dinv, csr);

  // ---- layer 1: gemm1 -> aggregate1 (+fused gemm2) ----
  gemm1_kernel<<<gemm_blocks, 256, 0, stream>>>(x, W1, h1, N);
  agg1_gemm2_kernel<<<agg_blocks, 256, 0, stream>>>(
      (const ushort4*)h1, offs, csr, dinv, (const float4*)b1, W2, h2, N);

  // ---- layer 2: aggregate2 -> out ----
  agg2_kernel<<<agg_blocks, 256, 0, stream>>>(
      (const ushort4*)h2, offs, csr, dinv, (const float4*)b2, (float4*)out, N);
}